// Round 1
// baseline (546.616 us; speedup 1.0000x reference)
//
#include <hip/hip_runtime.h>
#include <cstdint>
#include <cstddef>

#define DEVI __device__ __forceinline__

typedef __attribute__((ext_vector_type(8))) short s16x8;
typedef __attribute__((ext_vector_type(8))) unsigned short u16x8;
typedef __attribute__((ext_vector_type(4))) float f32x4;
typedef unsigned short u16;

static constexpr int Bc = 2, Tc = 2048, Hc = 16, DMc = 1024;

DEVI float bf2f(u16 u){ unsigned int x = ((unsigned int)u) << 16; return __builtin_bit_cast(float, x); }
DEVI u16 f2bf(float f){
  unsigned int u = __builtin_bit_cast(unsigned int, f);
  u += 0x7FFFu + ((u >> 16) & 1u);
  return (u16)(u >> 16);
}

DEVI float waveSum(float v){
  #pragma unroll
  for (int m = 1; m < 64; m <<= 1) v += __shfl_xor(v, m);
  return v;
}

DEVI void gload16(const void* g, void* l){
  __builtin_amdgcn_global_load_lds((const __attribute__((address_space(1))) void*)g,
                                   (__attribute__((address_space(3))) void*)l, 16, 0, 0);
}

// ---------------- fp32 -> bf16 convert ----------------
__global__ __launch_bounds__(256) void cvt_f32_bf16(const float* __restrict__ in,
                                                    u16* __restrict__ out, int n4){
  int i = blockIdx.x * blockDim.x + threadIdx.x;
  int stride = gridDim.x * blockDim.x;
  for (int idx = i; idx < n4; idx += stride){
    float4 v = ((const float4*)in)[idx];
    ushort4 o;
    o.x = f2bf(v.x); o.y = f2bf(v.y); o.z = f2bf(v.z); o.w = f2bf(v.w);
    ((ushort4*)out)[idx] = o;
  }
}

// ---------------- GEMM: C[m,n] = sum_k A[m,k] * W[n,k] (both row-major bf16) ----------------
// EPI 0: fp32 out (+ optional bias)
// EPI 1: bf16 out remapped to qkv layout ((b*H+h)*T + t)*192 + e
// EPI 2: bf16 out, val = (acc + bias[n]) * scale[n] * smul
template<int EPI>
__global__ __launch_bounds__(256) void gemm_bt(
    const u16* __restrict__ A, int lda, const u16* __restrict__ W,
    float* __restrict__ outF, u16* __restrict__ outB,
    const float* __restrict__ bias, const float* __restrict__ scale, float smul,
    int M, int N, int K)
{
  __shared__ u16 lA[128 * 32];
  __shared__ u16 lB[128 * 32];
  const int tid = threadIdx.x, lane = tid & 63;
  const int wave = tid >> 6, wm = wave >> 1, wn = wave & 1;
  const int m0 = blockIdx.y * 128, n0 = blockIdx.x * 128;
  f32x4 acc[4][4] = {};
  const int kT = K >> 5;
  char* lAc = (char*)lA;
  char* lBc = (char*)lB;
  const int wuni = (tid & ~63);

  for (int kt = 0; kt < kT; ++kt){
    const int k0 = kt << 5;
    __syncthreads();
    #pragma unroll
    for (int j = 0; j < 2; ++j){
      int idx = j * 256 + tid;
      gload16(A + (size_t)(m0 + (idx >> 2)) * lda + k0 + ((idx & 3) << 3),
              lAc + ((j * 256 + wuni) << 4));
    }
    #pragma unroll
    for (int j = 0; j < 2; ++j){
      int idx = j * 256 + tid;
      gload16(W + (size_t)(n0 + (idx >> 2)) * K + k0 + ((idx & 3) << 3),
              lBc + ((j * 256 + wuni) << 4));
    }
    __syncthreads();

    s16x8 aF[4], bF[4];
    #pragma unroll
    for (int i = 0; i < 4; ++i)
      aF[i] = *(const s16x8*)&lA[(wm * 64 + i * 16 + (lane & 15)) * 32 + ((lane >> 4) << 3)];
    #pragma unroll
    for (int j = 0; j < 4; ++j)
      bF[j] = *(const s16x8*)&lB[(wn * 64 + j * 16 + (lane & 15)) * 32 + ((lane >> 4) << 3)];
    #pragma unroll
    for (int i = 0; i < 4; ++i)
      #pragma unroll
      for (int j = 0; j < 4; ++j)
        acc[i][j] = __builtin_amdgcn_mfma_f32_16x16x32_bf16(aF[i], bF[j], acc[i][j], 0, 0, 0);
  }

  const int rb = m0 + wm * 64 + ((lane >> 4) << 2);
  const int cb = n0 + wn * 64 + (lane & 15);
  #pragma unroll
  for (int i = 0; i < 4; ++i){
    #pragma unroll
    for (int j = 0; j < 4; ++j){
      #pragma unroll
      for (int r = 0; r < 4; ++r){
        const int row = rb + i * 16 + r;
        const int col = cb + j * 16;
        float v = acc[i][j][r];
        if (EPI == 0){
          if (bias) v += bias[col];
          outF[(size_t)row * N + col] = v;
        } else if (EPI == 1){
          const int b = row >> 11;           // T = 2048
          const int t = row & (Tc - 1);
          const int h = col / 192;
          const int e = col - h * 192;
          outB[(((size_t)(b * Hc + h)) * Tc + t) * 192 + e] = f2bf(v);
        } else {
          v = (v + bias[col]) * (scale[col] * smul);
          outB[(size_t)row * N + col] = f2bf(v);
        }
      }
    }
  }
}

// ---------------- RoPE + justnorm + sqk on Q,K in-place (qkv layout, bf16) ----------------
__global__ __launch_bounds__(256) void rope_norm(u16* __restrict__ qkv,
                                                 const float* __restrict__ sqk){
  const int lane = threadIdx.x & 63;
  const int idx = blockIdx.x * 4 + (threadIdx.x >> 6);  // row over B*H*T
  const int t = idx & (Tc - 1);
  const int h = (idx >> 11) & (Hc - 1);
  u16* row = qkv + (size_t)idx * 192;
  float q = bf2f(row[lane]), k = bf2f(row[64 + lane]);
  const int fi = lane & 31;
  float invf = powf(10000.0f, -(float)fi / 32.0f);
  float ang = (float)t * invf;
  float sn, cs;
  sincosf(ang, &sn, &cs);
  float qo = __shfl_xor(q, 32), ko = __shfl_xor(k, 32);
  float rq = (lane < 32) ? -qo : qo;
  float rk = (lane < 32) ? -ko : ko;
  float qn = q * cs + rq * sn;
  float kn = k * cs + rk * sn;
  float sq = waveSum(qn * qn), sk = waveSum(kn * kn);
  float scl = sqk[h * 64 + lane];
  row[lane]      = f2bf(qn / sqrtf(sq) * scl);
  row[64 + lane] = f2bf(kn / sqrtf(sk) * scl);
}

// ---------------- causal flash attention: 1 wave = 16 q rows ----------------
__global__ __launch_bounds__(256) void attn_kernel(const u16* __restrict__ qkv,
                                                   float* __restrict__ o){
  const int tid = threadIdx.x, lane = tid & 63, wave = tid >> 6;
  const int bh = blockIdx.y;
  const int q0 = blockIdx.x * 64 + wave * 16;
  const int g = lane >> 4, cl = lane & 15;
  const u16* base = qkv + (size_t)bh * Tc * 192;

  s16x8 qF[2];
  {
    const u16* qrow = base + (size_t)(q0 + cl) * 192 + (g << 3);
    qF[0] = *(const s16x8*)qrow;
    qF[1] = *(const s16x8*)(qrow + 32);
  }
  f32x4 oF[4] = {};
  float mrow[4], lrow[4];
  #pragma unroll
  for (int r = 0; r < 4; ++r){ mrow[r] = -3.0e38f; lrow[r] = 0.0f; }

  __shared__ u16 pT[4][512];
  u16* pw = pT[wave];
  const int nsteps = (q0 + 15) / 32 + 1;

  for (int kt = 0; kt < nsteps; ++kt){
    const int kb = kt * 32;
    f32x4 sF[2] = {};
    #pragma unroll
    for (int c16 = 0; c16 < 2; ++c16){
      const u16* kr = base + (size_t)(kb + c16 * 16 + cl) * 192 + 64 + (g << 3);
      s16x8 kf0 = *(const s16x8*)kr;
      s16x8 kf1 = *(const s16x8*)(kr + 32);
      sF[c16] = __builtin_amdgcn_mfma_f32_16x16x32_bf16(qF[0], kf0, sF[c16], 0, 0, 0);
      sF[c16] = __builtin_amdgcn_mfma_f32_16x16x32_bf16(qF[1], kf1, sF[c16], 0, 0, 0);
    }
    #pragma unroll
    for (int r = 0; r < 4; ++r){
      const int qg = q0 + g * 4 + r;
      float s0 = sF[0][r] * 32.0f; if (kb + cl > qg)      s0 = -3.0e38f;
      float s1 = sF[1][r] * 32.0f; if (kb + 16 + cl > qg) s1 = -3.0e38f;
      float mx = fmaxf(s0, s1);
      mx = fmaxf(mx, __shfl_xor(mx, 1));
      mx = fmaxf(mx, __shfl_xor(mx, 2));
      mx = fmaxf(mx, __shfl_xor(mx, 4));
      mx = fmaxf(mx, __shfl_xor(mx, 8));
      const float mnew = fmaxf(mrow[r], mx);
      const float al = __expf(mrow[r] - mnew);
      const float p0 = __expf(s0 - mnew);
      const float p1 = __expf(s1 - mnew);
      float ps = p0 + p1;
      ps += __shfl_xor(ps, 1);
      ps += __shfl_xor(ps, 2);
      ps += __shfl_xor(ps, 4);
      ps += __shfl_xor(ps, 8);
      lrow[r] = lrow[r] * al + ps;
      mrow[r] = mnew;
      oF[0][r] *= al; oF[1][r] *= al; oF[2][r] *= al; oF[3][r] *= al;
      pw[(g * 4 + r) * 32 + cl]      = f2bf(p0);
      pw[(g * 4 + r) * 32 + 16 + cl] = f2bf(p1);
    }
    asm volatile("s_waitcnt lgkmcnt(0)" ::: "memory");
    __builtin_amdgcn_sched_barrier(0);
    s16x8 pF = *(const s16x8*)&pw[cl * 32 + (g << 3)];
    const u16* vbase = base + (size_t)(kb + (g << 3)) * 192 + 128 + cl;
    #pragma unroll
    for (int d0 = 0; d0 < 4; ++d0){
      s16x8 vF;
      #pragma unroll
      for (int j = 0; j < 8; ++j) vF[j] = (short)vbase[(size_t)j * 192 + d0 * 16];
      oF[d0] = __builtin_amdgcn_mfma_f32_16x16x32_bf16(pF, vF, oF[d0], 0, 0, 0);
    }
    asm volatile("" ::: "memory");  // keep next iter's P writes after this iter's P reads
  }

  float invl[4];
  #pragma unroll
  for (int r = 0; r < 4; ++r) invl[r] = 1.0f / lrow[r];
  const int b = bh / Hc, h = bh % Hc;
  #pragma unroll
  for (int d0 = 0; d0 < 4; ++d0){
    #pragma unroll
    for (int r = 0; r < 4; ++r){
      const int qg = q0 + g * 4 + r;
      o[((size_t)(b * Tc + qg)) * DMc + h * 64 + d0 * 16 + cl] = oF[d0][r] * invl[r];
    }
  }
}

// ---------------- row-wise justnorm of 1024-row -> bf16 ----------------
__global__ __launch_bounds__(256) void rownorm1024(const float* __restrict__ in,
                                                   u16* __restrict__ out){
  const int row = blockIdx.x, tid = threadIdx.x;
  const float* r = in + (size_t)row * 1024;
  float v[4]; float ss = 0.0f;
  #pragma unroll
  for (int i = 0; i < 4; ++i){ v[i] = r[tid + i * 256]; ss += v[i] * v[i]; }
  __shared__ float red[4];
  ss = waveSum(ss);
  if ((tid & 63) == 0) red[tid >> 6] = ss;
  __syncthreads();
  const float tot = red[0] + red[1] + red[2] + red[3];
  const float inv = 1.0f / sqrtf(tot);
  #pragma unroll
  for (int i = 0; i < 4; ++i) out[(size_t)row * 1024 + tid + i * 256] = f2bf(v[i] * inv);
}

// ---------------- x2 = justnorm(justnorm(x) + lr*(justnorm(t)-justnorm(x))) ----------------
__global__ __launch_bounds__(256) void x2_kernel(const float* __restrict__ x,
                                                 const float* __restrict__ t,
                                                 const float* __restrict__ alpha,
                                                 float* __restrict__ x2f,
                                                 u16* __restrict__ x2b){
  const int row = blockIdx.x, tid = threadIdx.x, lane = tid & 63, wv = tid >> 6;
  const float* xr = x + (size_t)row * 1024;
  const float* tr = t + (size_t)row * 1024;
  float xv[4], tv[4]; float sx = 0.0f, st = 0.0f;
  #pragma unroll
  for (int i = 0; i < 4; ++i){
    xv[i] = xr[tid + i * 256]; sx += xv[i] * xv[i];
    tv[i] = tr[tid + i * 256]; st += tv[i] * tv[i];
  }
  __shared__ float red[8];
  sx = waveSum(sx); st = waveSum(st);
  if (lane == 0){ red[wv] = sx; red[4 + wv] = st; }
  __syncthreads();
  sx = red[0] + red[1] + red[2] + red[3];
  st = red[4] + red[5] + red[6] + red[7];
  const float ix = 1.0f / sqrtf(sx), it = 1.0f / sqrtf(st);
  float yv[4]; float sy = 0.0f;
  #pragma unroll
  for (int i = 0; i < 4; ++i){
    const int c = tid + i * 256;
    const float lr = fabsf(alpha[c] * 1.6f);  // 0.05 / C^-0.5 = 0.05*32
    const float a = xv[i] * ix, bn = tv[i] * it;
    yv[i] = a + lr * (bn - a);
    sy += yv[i] * yv[i];
  }
  sy = waveSum(sy);
  __syncthreads();
  if (lane == 0) red[wv] = sy;
  __syncthreads();
  sy = red[0] + red[1] + red[2] + red[3];
  const float iy = 1.0f / sqrtf(sy);
  #pragma unroll
  for (int i = 0; i < 4; ++i){
    const int c = tid + i * 256;
    const float v = yv[i] * iy;
    x2f[(size_t)row * 1024 + c] = v;
    x2b[(size_t)row * 1024 + c] = f2bf(v);
  }
}

// ---------------- uv (bf16, pre-scaled) -> justnorm row 8192 -> res = u*silu(v) in-place ----------------
__global__ __launch_bounds__(256) void uvres_kernel(u16* __restrict__ uv){
  const int row = blockIdx.x, tid = threadIdx.x;
  u16* p = uv + (size_t)row * 8192;
  float uvv[32]; float ss = 0.0f;
  const u16x8* su = (const u16x8*)(p + tid * 16);
  const u16x8* sv = (const u16x8*)(p + 4096 + tid * 16);
  u16x8 a0 = su[0], a1 = su[1], b0 = sv[0], b1 = sv[1];
  #pragma unroll
  for (int j = 0; j < 8; ++j){
    uvv[j]      = bf2f(a0[j]); uvv[8 + j]  = bf2f(a1[j]);
    uvv[16 + j] = bf2f(b0[j]); uvv[24 + j] = bf2f(b1[j]);
  }
  #pragma unroll
  for (int j = 0; j < 32; ++j) ss += uvv[j] * uvv[j];
  __shared__ float red[4];
  ss = waveSum(ss);
  if ((tid & 63) == 0) red[tid >> 6] = ss;
  __syncthreads();
  const float tot = red[0] + red[1] + red[2] + red[3];
  const float inv = 1.0f / sqrtf(tot);
  #pragma unroll
  for (int j = 0; j < 16; ++j){
    const float un = uvv[j] * inv;
    const float vn = uvv[16 + j] * inv;
    const float sil = vn / (1.0f + expf(-vn));
    p[tid * 16 + j] = f2bf(un * sil);
  }
}

// ---------------- final: justnorm(justnorm(x2) + lr2*(justnorm(t2)-justnorm(x2))) ----------------
__global__ __launch_bounds__(256) void final_kernel(const float* __restrict__ x2,
                                                    const float* __restrict__ t2,
                                                    const float* __restrict__ alpha,
                                                    float* __restrict__ out){
  const int row = blockIdx.x, tid = threadIdx.x, lane = tid & 63, wv = tid >> 6;
  const float* a = x2 + (size_t)row * 1024;
  const float* b = t2 + (size_t)row * 1024;
  float av[4], bv[4]; float sa = 0.0f, sb = 0.0f;
  #pragma unroll
  for (int i = 0; i < 4; ++i){
    av[i] = a[tid + i * 256]; sa += av[i] * av[i];
    bv[i] = b[tid + i * 256]; sb += bv[i] * bv[i];
  }
  __shared__ float red[8];
  sa = waveSum(sa); sb = waveSum(sb);
  if (lane == 0){ red[wv] = sa; red[4 + wv] = sb; }
  __syncthreads();
  sa = red[0] + red[1] + red[2] + red[3];
  sb = red[4] + red[5] + red[6] + red[7];
  const float ia = 1.0f / sqrtf(sa), ib = 1.0f / sqrtf(sb);
  float yv[4]; float sy = 0.0f;
  #pragma unroll
  for (int i = 0; i < 4; ++i){
    const int c = tid + i * 256;
    const float lr = fabsf(alpha[c] * 0.05f);
    const float an = av[i] * ia, bn = bv[i] * ib;
    yv[i] = an + lr * (bn - an);
    sy += yv[i] * yv[i];
  }
  sy = waveSum(sy);
  __syncthreads();
  if (lane == 0) red[wv] = sy;
  __syncthreads();
  sy = red[0] + red[1] + red[2] + red[3];
  const float iy = 1.0f / sqrtf(sy);
  #pragma unroll
  for (int i = 0; i < 4; ++i)
    out[(size_t)row * 1024 + tid + i * 256] = yv[i] * iy;
}

extern "C" void kernel_launch(void* const* d_in, const int* in_sizes, int n_in,
                              void* d_out, int out_size, void* d_ws, size_t ws_size,
                              hipStream_t stream) {
  const float* x          = (const float*)d_in[0];
  const float* Wqkv       = (const float*)d_in[1];
  const float* sqk        = (const float*)d_in[2];
  const float* W_O        = (const float*)d_in[3];
  const float* attn_alpha = (const float*)d_in[4];
  const float* Wu_w       = (const float*)d_in[5];
  const float* Wu_b       = (const float*)d_in[6];
  const float* suv        = (const float*)d_in[7];
  const float* Wv_w       = (const float*)d_in[8];
  const float* Wv_b       = (const float*)d_in[9];
  const float* mlp_alpha  = (const float*)d_in[10];
  float* out = (float*)d_out;

  char* ws = (char*)d_ws;
  // workspace layout (128 MiB total, aliased):
  u16*   wbuf = (u16*)(ws);                       // 16 MiB: bf16 weights (reused per GEMM)
  u16*   abuf = (u16*)(ws + 16777216);            //  8 MiB: bf16 A operand (xb -> ob_norm -> x2b)
  u16*   qkvb = (u16*)(ws + 25165824);            // 24 MiB: qkv bf16; later t fp32; later t2 fp32
  float* tbuf = (float*)(ws + 25165824);
  float* aout = (float*)(ws + 50331648);          // 16 MiB: attn out fp32; later x2 fp32
  float* x2f  = (float*)(ws + 50331648);
  u16*   uvb  = (u16*)(ws + 67108864);            // 64 MiB: uv bf16 (res overwrites u-half)

  const int M = Bc * Tc;  // 4096

  auto cvt = [&](const float* in, u16* o, int n){
    int n4 = n / 4;
    int blocks = (n4 + 255) / 256;
    if (blocks > 4096) blocks = 4096;
    cvt_f32_bf16<<<dim3(blocks), dim3(256), 0, stream>>>(in, o, n4);
  };

  // 1. qkv = x @ Wqkv^T  (remapped into (b,h,t,e) bf16)
  cvt(x, abuf, M * DMc);
  cvt(Wqkv, wbuf, Hc * 192 * DMc);
  gemm_bt<1><<<dim3(3072 / 128, M / 128), 256, 0, stream>>>(
      abuf, DMc, wbuf, nullptr, qkvb, nullptr, nullptr, 0.0f, M, 3072, DMc);

  // 2. RoPE + justnorm + sqk on Q,K
  rope_norm<<<dim3(Bc * Hc * Tc / 4), 256, 0, stream>>>(qkvb, sqk);

  // 3. causal flash attention -> aout (b,t,h*64+d) fp32
  attn_kernel<<<dim3(Tc / 64, Bc * Hc), 256, 0, stream>>>(qkvb, aout);

  // 4. justnorm rows -> bf16, then t = . @ W_O^T (fp32)
  rownorm1024<<<dim3(M), 256, 0, stream>>>(aout, abuf);
  cvt(W_O, wbuf, DMc * DMc);
  gemm_bt<0><<<dim3(DMc / 128, M / 128), 256, 0, stream>>>(
      abuf, DMc, wbuf, tbuf, nullptr, nullptr, nullptr, 0.0f, M, DMc, DMc);

  // 5. x2 residual mix
  x2_kernel<<<dim3(M), 256, 0, stream>>>(x, tbuf, attn_alpha, x2f, abuf);

  // 6. uv = (x2 @ Wu^T + b) * suv * 32  (bf16)
  cvt(Wu_w, wbuf, 8192 * DMc);
  gemm_bt<2><<<dim3(8192 / 128, M / 128), 256, 0, stream>>>(
      abuf, DMc, wbuf, nullptr, uvb, Wu_b, suv, 32.0f, M, 8192, DMc);

  // 7. row-norm 8192 + u*silu(v) in-place into u half
  uvres_kernel<<<dim3(M), 256, 0, stream>>>(uvb);

  // 8. t2 = res @ Wv^T + b (fp32)
  cvt(Wv_w, wbuf, DMc * 4096);
  gemm_bt<0><<<dim3(DMc / 128, M / 128), 256, 0, stream>>>(
      uvb, 8192, wbuf, tbuf, nullptr, Wv_b, nullptr, 0.0f, M, DMc, 4096);

  // 9. final residual mix -> d_out
  final_kernel<<<dim3(M), 256, 0, stream>>>(x2f, tbuf, mlp_alpha, out);
}